// Round 6
// baseline (778.765 us; speedup 1.0000x reference)
//
#include <hip/hip_runtime.h>
#include <math.h>

#define NB 256      // batch / time steps
#define NV 100      // visits
#define NC 40       // codes per visit
#define NE 128      // embed dim (LSTM "batch")
#define NH 100      // hidden (== feat)
#define NG 400      // 4*NH

// ws layout (float elements)
#define OFF_SUM   0
#define N_SUM     (NB*NV*NE)                 // 3,276,800  (x2 viewed [32768][100])
#define OFF_PRE   (OFF_SUM + N_SUM)
#define N_PRE     (NB*NE*NG)                 // 13,107,200
#define OFF_TRUH  (OFF_PRE + N_PRE)
#define N_TRUH    (NB*NE)                    // 32,768
#define OFF_LAST  (OFF_TRUH + N_TRUH)        // ints, 256

// ---------------------------------------------------------------- kernel 1
// masked embedding sum + last-visit segment max. mask/diag rows staged in
// LDS once (they're block-uniform) instead of 80 broadcast global loads.
__global__ __launch_bounds__(128) void k_embed(
    const int* __restrict__ diag, const float* __restrict__ mask,
    const float* __restrict__ table, float* __restrict__ sumembed,
    int* __restrict__ last) {
  __shared__ float m_s[NC];
  __shared__ int   d_s[NC];
  int bv = blockIdx.x;              // 0..25599
  int b  = bv / NV;
  int v  = bv - b * NV;
  int base = bv * NC;
  int e = threadIdx.x;              // 0..127
  if (e < NC) { m_s[e] = mask[base + e]; d_s[e] = diag[base + e]; }
  __syncthreads();
  float acc = 0.f;
  for (int c = 0; c < NC; ++c) {
    float m = m_s[c];
    if (m != 0.f) {                 // block-uniform branch
      acc = fmaf(m, table[d_s[c] * NE + e], acc);
    }
  }
  sumembed[bv * NE + e] = acc;
  if (e == 0) {
    float msum = 0.f;
    for (int c = 0; c < NC; ++c) msum += m_s[c];
    if (msum > 0.f) atomicMax(&last[b], v);
  }
}

// ---------------------------------------------------------------- kernel 2
// pre[t*128+e][j] = x2[m][:] . W_ih[j][:] + (b_ih[j]+b_hh[j])
// M=32768, K=100, N=400.  64x64 tiles, 4x4 register tiles.
__global__ __launch_bounds__(256) void k_pregemm(
    const float* __restrict__ x2, const float* __restrict__ Wih,
    const float* __restrict__ bih, const float* __restrict__ bhh,
    float* __restrict__ pre) {
  __shared__ __align__(16) float As[100][68];   // [k][m], stride 68 => 16B aligned rows
  __shared__ __align__(16) float Bs[100][68];   // [k][n]
  __shared__ __align__(16) float bias_s[64];
  const int m0 = blockIdx.x * 64;
  const int n0 = blockIdx.y * 64;
  const int tid = threadIdx.x;

  for (int idx = tid; idx < 6400; idx += 256) {
    int m = idx / 100, k = idx - m * 100;
    As[k][m] = x2[(m0 + m) * 100 + k];          // coalesced along k
  }
  for (int idx = tid; idx < 6400; idx += 256) {
    int n = idx / 100, k = idx - n * 100;
    int j = n0 + n;
    Bs[k][n] = (j < NG) ? Wih[j * 100 + k] : 0.f;
  }
  if (tid < 64) {
    int j = n0 + tid;
    bias_s[tid] = (j < NG) ? (bih[j] + bhh[j]) : 0.f;
  }
  __syncthreads();

  const int tm = tid & 15, tn = tid >> 4;       // 16x16 thread grid, 4x4 each
  float acc[4][4] = {};
  #pragma unroll 4
  for (int k = 0; k < 100; ++k) {
    float4 a  = *(const float4*)&As[k][tm * 4];
    float4 bb = *(const float4*)&Bs[k][tn * 4];
    acc[0][0] = fmaf(a.x, bb.x, acc[0][0]); acc[0][1] = fmaf(a.x, bb.y, acc[0][1]);
    acc[0][2] = fmaf(a.x, bb.z, acc[0][2]); acc[0][3] = fmaf(a.x, bb.w, acc[0][3]);
    acc[1][0] = fmaf(a.y, bb.x, acc[1][0]); acc[1][1] = fmaf(a.y, bb.y, acc[1][1]);
    acc[1][2] = fmaf(a.y, bb.z, acc[1][2]); acc[1][3] = fmaf(a.y, bb.w, acc[1][3]);
    acc[2][0] = fmaf(a.z, bb.x, acc[2][0]); acc[2][1] = fmaf(a.z, bb.y, acc[2][1]);
    acc[2][2] = fmaf(a.z, bb.z, acc[2][2]); acc[2][3] = fmaf(a.z, bb.w, acc[2][3]);
    acc[3][0] = fmaf(a.w, bb.x, acc[3][0]); acc[3][1] = fmaf(a.w, bb.y, acc[3][1]);
    acc[3][2] = fmaf(a.w, bb.z, acc[3][2]); acc[3][3] = fmaf(a.w, bb.w, acc[3][3]);
  }

  if (n0 + tn * 4 < NG) {                       // whole float4 valid or none (400%4==0)
    float4 bb = *(const float4*)&bias_s[tn * 4];
    #pragma unroll
    for (int im = 0; im < 4; ++im) {
      int m = m0 + tm * 4 + im;
      float4 st;
      st.x = acc[im][0] + bb.x; st.y = acc[im][1] + bb.y;
      st.z = acc[im][2] + bb.z; st.w = acc[im][3] + bb.w;
      *(float4*)&pre[m * NG + n0 + tn * 4] = st;
    }
  }
}

// ---------------------------------------------------------------- kernel 3
// sequential LSTM, J=4: 128 blocks (one per e), 128 threads; thread j<100
// owns ALL FOUR gate rows (j, 100+j, 200+j, 300+j) = 100 float4 = 400 weight
// VGPRs. h-broadcast traffic drops 4x vs J=1 (the R1-R5 wall: 160KB/CU/step
// of per-FMA operand delivery, whether via scratch-remat(L1) or LDS return).
// Thread j computes i,f,g,o for hidden index j itself -> no g_s exchange,
// c and h stay in-register, 2 barriers/step.
// Anti-remat: const+restrict loads are invariant -> RA reloads them in-loop
// (R5: budget 256, used 88, time unchanged). asm pin makes each weight an
// asm def, which cannot be rematerialized. waves_per_eu(1,1): 512-reg budget.
__device__ __forceinline__ float fast_sigmoid(float x) {
  return 1.f / (1.f + __expf(-x));
}
__device__ __forceinline__ float fast_tanh(float x) {
  float ax = fabsf(x);
  float e  = __expf(-2.f * ax);
  float t  = (1.f - e) / (1.f + e);
  return x < 0.f ? -t : t;
}

#define FMA4(A, W, H)                                                     \
  A = fmaf((H).x, (W).x, A); A = fmaf((H).y, (W).y, A);                   \
  A = fmaf((H).z, (W).z, A); A = fmaf((H).w, (W).w, A)

#define PIN4(v) asm volatile("" : "+v"((v).x), "+v"((v).y), "+v"((v).z), "+v"((v).w))

#define DECL25(p) float4 p##0,p##1,p##2,p##3,p##4,p##5,p##6,p##7,p##8,p##9, \
  p##10,p##11,p##12,p##13,p##14,p##15,p##16,p##17,p##18,p##19,p##20,p##21,  \
  p##22,p##23,p##24

#define LOAD25(p, src)                                                      \
  p##0=(src)[0]; p##1=(src)[1]; p##2=(src)[2]; p##3=(src)[3]; p##4=(src)[4];\
  p##5=(src)[5]; p##6=(src)[6]; p##7=(src)[7]; p##8=(src)[8]; p##9=(src)[9];\
  p##10=(src)[10]; p##11=(src)[11]; p##12=(src)[12]; p##13=(src)[13];       \
  p##14=(src)[14]; p##15=(src)[15]; p##16=(src)[16]; p##17=(src)[17];       \
  p##18=(src)[18]; p##19=(src)[19]; p##20=(src)[20]; p##21=(src)[21];       \
  p##22=(src)[22]; p##23=(src)[23]; p##24=(src)[24]

#define PIN25(p)                                                            \
  PIN4(p##0); PIN4(p##1); PIN4(p##2); PIN4(p##3); PIN4(p##4);               \
  PIN4(p##5); PIN4(p##6); PIN4(p##7); PIN4(p##8); PIN4(p##9);               \
  PIN4(p##10); PIN4(p##11); PIN4(p##12); PIN4(p##13); PIN4(p##14);          \
  PIN4(p##15); PIN4(p##16); PIN4(p##17); PIN4(p##18); PIN4(p##19);          \
  PIN4(p##20); PIN4(p##21); PIN4(p##22); PIN4(p##23); PIN4(p##24)

// one h-quad feeds 16 FMAs (4 rows x 4 lanes of k)
#define DOT4(q, AI, AF, AG, AO) {                                           \
  float4 hv = h4[q];                                                        \
  FMA4(AI, wi##q, hv); FMA4(AF, wf##q, hv);                                 \
  FMA4(AG, wg##q, hv); FMA4(AO, wo##q, hv); }

__global__ __launch_bounds__(128)
__attribute__((amdgpu_waves_per_eu(1, 1)))
void k_lstm(
    const float* __restrict__ pre, const float* __restrict__ Whh,
    const int* __restrict__ last, float* __restrict__ truh) {
  __shared__ __align__(16) float h_s[NH];
  __shared__ int last_s[NB];
  const int e = blockIdx.x;         // 0..127
  const int j = threadIdx.x;        // active < 100

  DECL25(wi); DECL25(wf); DECL25(wg); DECL25(wo);
  if (j < NH) {
    const float4* ri = (const float4*)(Whh + (j        ) * NH);
    const float4* rf = (const float4*)(Whh + (j + 1*NH) * NH);
    const float4* rg = (const float4*)(Whh + (j + 2*NH) * NH);
    const float4* ro = (const float4*)(Whh + (j + 3*NH) * NH);
    LOAD25(wi, ri); LOAD25(wf, rf); LOAD25(wg, rg); LOAD25(wo, ro);
    PIN25(wi); PIN25(wf); PIN25(wg); PIN25(wo);
    h_s[j] = 0.f;
  }
  last_s[j] = last[j];
  last_s[j + 128] = last[j + 128];
  float c = 0.f;

  const float* pb = pre + e * NG + j;           // + t*51200 per step
  float pi0 = 0.f, pf0 = 0.f, pg0 = 0.f, po0 = 0.f;
  float pi1 = 0.f, pf1 = 0.f, pg1 = 0.f, po1 = 0.f;
  float pi2 = 0.f, pf2 = 0.f, pg2 = 0.f, po2 = 0.f;
  if (j < NH) {
    pi0 = pb[0*51200 +   0]; pf0 = pb[0*51200 + 100];
    pg0 = pb[0*51200 + 200]; po0 = pb[0*51200 + 300];
    pi1 = pb[1*51200 +   0]; pf1 = pb[1*51200 + 100];
    pg1 = pb[1*51200 + 200]; po1 = pb[1*51200 + 300];
    pi2 = pb[2*51200 +   0]; pf2 = pb[2*51200 + 100];
    pg2 = pb[2*51200 + 200]; po2 = pb[2*51200 + 300];
  }
  __syncthreads();

  for (int t = 0; t < NB; ++t) {
    float pi3 = 0.f, pf3 = 0.f, pg3 = 0.f, po3 = 0.f;
    if (j < NH && t + 3 < NB) {
      const float* pn = pb + (t + 3) * 51200;
      pi3 = pn[0]; pf3 = pn[100]; pg3 = pn[200]; po3 = pn[300];
    }

    float hval = 0.f;
    if (j < NH) {
      // 8 accumulator chains (2 per gate), 25 broadcast b128 h-reads
      float ai0 = pi0, af0 = pf0, ag0 = pg0, ao0 = po0;
      float ai1 = 0.f, af1 = 0.f, ag1 = 0.f, ao1 = 0.f;
      const float4* h4 = (const float4*)h_s;
      DOT4( 0, ai0, af0, ag0, ao0); DOT4( 1, ai1, af1, ag1, ao1);
      DOT4( 2, ai0, af0, ag0, ao0); DOT4( 3, ai1, af1, ag1, ao1);
      DOT4( 4, ai0, af0, ag0, ao0); DOT4( 5, ai1, af1, ag1, ao1);
      DOT4( 6, ai0, af0, ag0, ao0); DOT4( 7, ai1, af1, ag1, ao1);
      DOT4( 8, ai0, af0, ag0, ao0); DOT4( 9, ai1, af1, ag1, ao1);
      DOT4(10, ai0, af0, ag0, ao0); DOT4(11, ai1, af1, ag1, ao1);
      DOT4(12, ai0, af0, ag0, ao0); DOT4(13, ai1, af1, ag1, ao1);
      DOT4(14, ai0, af0, ag0, ao0); DOT4(15, ai1, af1, ag1, ao1);
      DOT4(16, ai0, af0, ag0, ao0); DOT4(17, ai1, af1, ag1, ao1);
      DOT4(18, ai0, af0, ag0, ao0); DOT4(19, ai1, af1, ag1, ao1);
      DOT4(20, ai0, af0, ag0, ao0); DOT4(21, ai1, af1, ag1, ao1);
      DOT4(22, ai0, af0, ag0, ao0); DOT4(23, ai1, af1, ag1, ao1);
      DOT4(24, ai0, af0, ag0, ao0);
      float ig = fast_sigmoid(ai0 + ai1);
      float fg = fast_sigmoid(af0 + af1);
      float gg = fast_tanh   (ag0 + ag1);
      float og = fast_sigmoid(ao0 + ao1);
      c = fmaf(fg, c, ig * gg);
      hval = og * fast_tanh(c);
    }
    __syncthreads();                            // all reads of h_s(t-1) done
    if (j < NH) {
      h_s[j] = hval;
      if (j == last_s[t]) truh[t * NE + e] = hval;  // hs[b=t, e, last[t]]
    }
    __syncthreads();                            // h_s(t) visible

    pi0 = pi1; pf0 = pf1; pg0 = pg1; po0 = po1;
    pi1 = pi2; pf1 = pf2; pg1 = pg2; po1 = po2;
    pi2 = pi3; pf2 = pf3; pg2 = pg3; po2 = po3;
  }
}

// ---------------------------------------------------------------- kernel 4
// out[b] = sigmoid( truh[b,:] . fc_w + fc_b )
__global__ __launch_bounds__(128) void k_fc(
    const float* __restrict__ truh, const float* __restrict__ fcw,
    const float* __restrict__ fcb, float* __restrict__ out) {
  int b = blockIdx.x, t = threadIdx.x;
  float v = truh[b * NE + t] * fcw[t];
  #pragma unroll
  for (int o = 32; o > 0; o >>= 1) v += __shfl_down(v, o);
  __shared__ float s[2];
  if ((t & 63) == 0) s[t >> 6] = v;
  __syncthreads();
  if (t == 0) {
    float sum = s[0] + s[1] + fcb[0];
    out[b] = 1.f / (1.f + __expf(-sum));
  }
}

// ---------------------------------------------------------------- launch
extern "C" void kernel_launch(void* const* d_in, const int* in_sizes, int n_in,
                              void* d_out, int out_size, void* d_ws, size_t ws_size,
                              hipStream_t stream) {
  (void)in_sizes; (void)n_in; (void)out_size; (void)ws_size;
  const int*   diag  = (const int*)d_in[0];
  const float* mask  = (const float*)d_in[1];
  const float* table = (const float*)d_in[2];
  const float* Wih   = (const float*)d_in[3];
  const float* Whh   = (const float*)d_in[4];
  const float* bih   = (const float*)d_in[5];
  const float* bhh   = (const float*)d_in[6];
  const float* fcw   = (const float*)d_in[7];
  const float* fcb   = (const float*)d_in[8];

  float* ws       = (float*)d_ws;
  float* sumembed = ws + OFF_SUM;
  float* pre      = ws + OFF_PRE;
  float* truh     = ws + OFF_TRUH;
  int*   last     = (int*)(ws + OFF_LAST);
  float* out      = (float*)d_out;

  hipMemsetAsync(last, 0, NB * sizeof(int), stream);
  k_embed  <<<dim3(NB * NV), dim3(128), 0, stream>>>(diag, mask, table, sumembed, last);
  k_pregemm<<<dim3(512, 7),  dim3(256), 0, stream>>>(sumembed, Wih, bih, bhh, pre);
  k_lstm   <<<dim3(NE),      dim3(128), 0, stream>>>(pre, Whh, last, truh);
  k_fc     <<<dim3(NB),      dim3(128), 0, stream>>>(truh, fcw, fcb, out);
}

// Round 7
// 631.862 us; speedup vs baseline: 1.2325x; 1.2325x over previous
//
#include <hip/hip_runtime.h>
#include <math.h>

#define NB 256      // batch / time steps
#define NV 100      // visits
#define NC 40       // codes per visit
#define NE 128      // embed dim (LSTM "batch")
#define NH 100      // hidden (== feat)
#define NG 400      // 4*NH

// ws layout (float elements)
#define OFF_SUM   0
#define N_SUM     (NB*NV*NE)                 // 3,276,800  (x2 viewed [32768][100])
#define OFF_PRE   (OFF_SUM + N_SUM)
#define N_PRE     (NB*NE*NG)                 // 13,107,200
#define OFF_TRUH  (OFF_PRE + N_PRE)
#define N_TRUH    (NB*NE)                    // 32,768
#define OFF_LAST  (OFF_TRUH + N_TRUH)        // ints, 256

// ---------------------------------------------------------------- kernel 1
// masked embedding sum + last-visit segment max. mask/diag rows staged in
// LDS once (they're block-uniform) instead of 80 broadcast global loads.
__global__ __launch_bounds__(128) void k_embed(
    const int* __restrict__ diag, const float* __restrict__ mask,
    const float* __restrict__ table, float* __restrict__ sumembed,
    int* __restrict__ last) {
  __shared__ float m_s[NC];
  __shared__ int   d_s[NC];
  int bv = blockIdx.x;              // 0..25599
  int b  = bv / NV;
  int v  = bv - b * NV;
  int base = bv * NC;
  int e = threadIdx.x;              // 0..127
  if (e < NC) { m_s[e] = mask[base + e]; d_s[e] = diag[base + e]; }
  __syncthreads();
  float acc = 0.f;
  for (int c = 0; c < NC; ++c) {
    float m = m_s[c];
    if (m != 0.f) {                 // block-uniform branch
      acc = fmaf(m, table[d_s[c] * NE + e], acc);
    }
  }
  sumembed[bv * NE + e] = acc;
  if (e == 0) {
    float msum = 0.f;
    for (int c = 0; c < NC; ++c) msum += m_s[c];
    if (msum > 0.f) atomicMax(&last[b], v);
  }
}

// ---------------------------------------------------------------- kernel 2
// pre[t*128+e][j] = x2[m][:] . W_ih[j][:] + (b_ih[j]+b_hh[j])
// M=32768, K=100, N=400.  64x64 tiles, 4x4 register tiles.
__global__ __launch_bounds__(256) void k_pregemm(
    const float* __restrict__ x2, const float* __restrict__ Wih,
    const float* __restrict__ bih, const float* __restrict__ bhh,
    float* __restrict__ pre) {
  __shared__ __align__(16) float As[100][68];   // [k][m], stride 68 => 16B aligned rows
  __shared__ __align__(16) float Bs[100][68];   // [k][n]
  __shared__ __align__(16) float bias_s[64];
  const int m0 = blockIdx.x * 64;
  const int n0 = blockIdx.y * 64;
  const int tid = threadIdx.x;

  for (int idx = tid; idx < 6400; idx += 256) {
    int m = idx / 100, k = idx - m * 100;
    As[k][m] = x2[(m0 + m) * 100 + k];          // coalesced along k
  }
  for (int idx = tid; idx < 6400; idx += 256) {
    int n = idx / 100, k = idx - n * 100;
    int j = n0 + n;
    Bs[k][n] = (j < NG) ? Wih[j * 100 + k] : 0.f;
  }
  if (tid < 64) {
    int j = n0 + tid;
    bias_s[tid] = (j < NG) ? (bih[j] + bhh[j]) : 0.f;
  }
  __syncthreads();

  const int tm = tid & 15, tn = tid >> 4;       // 16x16 thread grid, 4x4 each
  float acc[4][4] = {};
  #pragma unroll 4
  for (int k = 0; k < 100; ++k) {
    float4 a  = *(const float4*)&As[k][tm * 4];
    float4 bb = *(const float4*)&Bs[k][tn * 4];
    acc[0][0] = fmaf(a.x, bb.x, acc[0][0]); acc[0][1] = fmaf(a.x, bb.y, acc[0][1]);
    acc[0][2] = fmaf(a.x, bb.z, acc[0][2]); acc[0][3] = fmaf(a.x, bb.w, acc[0][3]);
    acc[1][0] = fmaf(a.y, bb.x, acc[1][0]); acc[1][1] = fmaf(a.y, bb.y, acc[1][1]);
    acc[1][2] = fmaf(a.y, bb.z, acc[1][2]); acc[1][3] = fmaf(a.y, bb.w, acc[1][3]);
    acc[2][0] = fmaf(a.z, bb.x, acc[2][0]); acc[2][1] = fmaf(a.z, bb.y, acc[2][1]);
    acc[2][2] = fmaf(a.z, bb.z, acc[2][2]); acc[2][3] = fmaf(a.z, bb.w, acc[2][3]);
    acc[3][0] = fmaf(a.w, bb.x, acc[3][0]); acc[3][1] = fmaf(a.w, bb.y, acc[3][1]);
    acc[3][2] = fmaf(a.w, bb.z, acc[3][2]); acc[3][3] = fmaf(a.w, bb.w, acc[3][3]);
  }

  if (n0 + tn * 4 < NG) {                       // whole float4 valid or none (400%4==0)
    float4 bb = *(const float4*)&bias_s[tn * 4];
    #pragma unroll
    for (int im = 0; im < 4; ++im) {
      int m = m0 + tm * 4 + im;
      float4 st;
      st.x = acc[im][0] + bb.x; st.y = acc[im][1] + bb.y;
      st.z = acc[im][2] + bb.z; st.w = acc[im][3] + bb.w;
      *(float4*)&pre[m * NG + n0 + tn * 4] = st;
    }
  }
}

// ---------------------------------------------------------------- kernel 3
// sequential LSTM, J=2: 128 blocks (one per e), 256 threads (200 active);
// thread j<200 owns W_hh rows j and j+200 = 50 float4 = 200 weight VGPRs.
// HISTORY: R6's J=4 demanded ~415 regs; gfx950 caps ARCH VGPRs at 256/wave
// (512 is the unified VGPR+AGPR pool, not addressable by plain VALU) ->
// 160 regs spilled, 2 waves/CU, 512us. J=2 demand ~235 < 256: fits.
// Rows j<200 are i/f gates (sigmoid); rows 200+ are g/o. Thread j<100
// computes (i_j, g_j); thread j+100 computes (f_j, o_j) -> f,o exchanged
// via fo_s[200]. Branchless tanh = 2*sigmoid(2x)-1 avoids intra-wave
// divergence on the row-b activation.
// asm pins (R6-proven) stop invariant-load rematerialization (R5).
__device__ __forceinline__ float fast_sigmoid(float x) {
  return 1.f / (1.f + __expf(-x));
}
__device__ __forceinline__ float fast_tanh(float x) {
  return 2.f / (1.f + __expf(-2.f * x)) - 1.f;
}

#define FMA4(A, W, H)                                                     \
  A = fmaf((H).x, (W).x, A); A = fmaf((H).y, (W).y, A);                   \
  A = fmaf((H).z, (W).z, A); A = fmaf((H).w, (W).w, A)

#define PIN4(v) asm volatile("" : "+v"((v).x), "+v"((v).y), "+v"((v).z), "+v"((v).w))

#define DECL25(p) float4 p##0,p##1,p##2,p##3,p##4,p##5,p##6,p##7,p##8,p##9, \
  p##10,p##11,p##12,p##13,p##14,p##15,p##16,p##17,p##18,p##19,p##20,p##21,  \
  p##22,p##23,p##24

#define LOAD25(p, src)                                                      \
  p##0=(src)[0]; p##1=(src)[1]; p##2=(src)[2]; p##3=(src)[3]; p##4=(src)[4];\
  p##5=(src)[5]; p##6=(src)[6]; p##7=(src)[7]; p##8=(src)[8]; p##9=(src)[9];\
  p##10=(src)[10]; p##11=(src)[11]; p##12=(src)[12]; p##13=(src)[13];       \
  p##14=(src)[14]; p##15=(src)[15]; p##16=(src)[16]; p##17=(src)[17];       \
  p##18=(src)[18]; p##19=(src)[19]; p##20=(src)[20]; p##21=(src)[21];       \
  p##22=(src)[22]; p##23=(src)[23]; p##24=(src)[24]

#define PIN25(p)                                                            \
  PIN4(p##0); PIN4(p##1); PIN4(p##2); PIN4(p##3); PIN4(p##4);               \
  PIN4(p##5); PIN4(p##6); PIN4(p##7); PIN4(p##8); PIN4(p##9);               \
  PIN4(p##10); PIN4(p##11); PIN4(p##12); PIN4(p##13); PIN4(p##14);          \
  PIN4(p##15); PIN4(p##16); PIN4(p##17); PIN4(p##18); PIN4(p##19);          \
  PIN4(p##20); PIN4(p##21); PIN4(p##22); PIN4(p##23); PIN4(p##24)

// one h-quad feeds 8 FMAs (2 rows x 4 k-lanes)
#define DOT2(q, AA, AB) {                                                   \
  float4 hv = h4[q];                                                        \
  FMA4(AA, wa##q, hv); FMA4(AB, wb##q, hv); }

__global__ __launch_bounds__(256)
__attribute__((amdgpu_waves_per_eu(1, 1)))
void k_lstm(
    const float* __restrict__ pre, const float* __restrict__ Whh,
    const int* __restrict__ last, float* __restrict__ truh) {
  __shared__ __align__(16) float h_s[NH];
  __shared__ float fo_s[2 * NH];
  __shared__ int last_s[NB];
  const int e = blockIdx.x;         // 0..127
  const int j = threadIdx.x;        // active < 200

  DECL25(wa); DECL25(wb);
  if (j < 200) {
    const float4* ra = (const float4*)(Whh + j * NH);
    const float4* rb = (const float4*)(Whh + (j + 200) * NH);
    LOAD25(wa, ra); LOAD25(wb, rb);
    PIN25(wa); PIN25(wb);
  }
  if (j < NH) h_s[j] = 0.f;
  last_s[j] = last[j];
  float c = 0.f;

  const float* pb = pre + e * NG + j;           // + t*51200 per step
  float pa0 = 0.f, pb0 = 0.f, pa1 = 0.f, pb1 = 0.f, pa2 = 0.f, pb2 = 0.f;
  if (j < 200) {
    pa0 = pb[0*51200]; pb0 = pb[0*51200 + 200];
    pa1 = pb[1*51200]; pb1 = pb[1*51200 + 200];
    pa2 = pb[2*51200]; pb2 = pb[2*51200 + 200];
  }
  // branchless row-b activation constants: g-rows (j<100) use tanh =
  // 2*sigmoid(2x)-1; o-rows (j>=100) plain sigmoid.
  const float bA = (j < NH) ? 2.f : 1.f;        // output scale
  const float bB = (j < NH) ? 2.f : 1.f;        // input scale
  const float bC = (j < NH) ? -1.f : 0.f;       // output bias
  __syncthreads();

  for (int t = 0; t < NB; ++t) {
    float pa3 = 0.f, pb3 = 0.f;
    if (j < 200 && t + 3 < NB) {
      const float* pn = pb + (t + 3) * 51200;
      pa3 = pn[0]; pb3 = pn[200];
    }

    float iv = 0.f, gv = 0.f;
    if (j < 200) {
      float a0 = pa0, a1 = 0.f, b0 = pb0, b1 = 0.f;
      const float4* h4 = (const float4*)h_s;
      DOT2( 0, a0, b0); DOT2( 1, a1, b1);
      DOT2( 2, a0, b0); DOT2( 3, a1, b1);
      DOT2( 4, a0, b0); DOT2( 5, a1, b1);
      DOT2( 6, a0, b0); DOT2( 7, a1, b1);
      DOT2( 8, a0, b0); DOT2( 9, a1, b1);
      DOT2(10, a0, b0); DOT2(11, a1, b1);
      DOT2(12, a0, b0); DOT2(13, a1, b1);
      DOT2(14, a0, b0); DOT2(15, a1, b1);
      DOT2(16, a0, b0); DOT2(17, a1, b1);
      DOT2(18, a0, b0); DOT2(19, a1, b1);
      DOT2(20, a0, b0); DOT2(21, a1, b1);
      DOT2(22, a0, b0); DOT2(23, a1, b1);
      DOT2(24, a0, b0);
      float ga = a0 + a1;                       // i (j<100) or f (j>=100)
      float gb = b0 + b1;                       // g (j<100) or o (j>=100)
      float actA = fast_sigmoid(ga);
      float actB = bA / (1.f + __expf(-bB * gb)) + bC;
      if (j < NH) { iv = actA; gv = actB; }
      else        { fo_s[j - NH] = actA; fo_s[j] = actB; }
    }
    __syncthreads();                  // h_s(t-1) reads done; fo_s visible

    if (j < NH) {
      float fg = fo_s[j], og = fo_s[j + NH];
      c = fmaf(fg, c, iv * gv);
      float hval = og * fast_tanh(c);
      h_s[j] = hval;
      if (j == last_s[t]) truh[t * NE + e] = hval;  // hs[b=t, e, last[t]]
    }
    __syncthreads();                  // h_s(t) visible

    pa0 = pa1; pb0 = pb1;
    pa1 = pa2; pb1 = pb2;
    pa2 = pa3; pb2 = pb3;
  }
}

// ---------------------------------------------------------------- kernel 4
// out[b] = sigmoid( truh[b,:] . fc_w + fc_b )
__global__ __launch_bounds__(128) void k_fc(
    const float* __restrict__ truh, const float* __restrict__ fcw,
    const float* __restrict__ fcb, float* __restrict__ out) {
  int b = blockIdx.x, t = threadIdx.x;
  float v = truh[b * NE + t] * fcw[t];
  #pragma unroll
  for (int o = 32; o > 0; o >>= 1) v += __shfl_down(v, o);
  __shared__ float s[2];
  if ((t & 63) == 0) s[t >> 6] = v;
  __syncthreads();
  if (t == 0) {
    float sum = s[0] + s[1] + fcb[0];
    out[b] = 1.f / (1.f + __expf(-sum));
  }
}

// ---------------------------------------------------------------- launch
extern "C" void kernel_launch(void* const* d_in, const int* in_sizes, int n_in,
                              void* d_out, int out_size, void* d_ws, size_t ws_size,
                              hipStream_t stream) {
  (void)in_sizes; (void)n_in; (void)out_size; (void)ws_size;
  const int*   diag  = (const int*)d_in[0];
  const float* mask  = (const float*)d_in[1];
  const float* table = (const float*)d_in[2];
  const float* Wih   = (const float*)d_in[3];
  const float* Whh   = (const float*)d_in[4];
  const float* bih   = (const float*)d_in[5];
  const float* bhh   = (const float*)d_in[6];
  const float* fcw   = (const float*)d_in[7];
  const float* fcb   = (const float*)d_in[8];

  float* ws       = (float*)d_ws;
  float* sumembed = ws + OFF_SUM;
  float* pre      = ws + OFF_PRE;
  float* truh     = ws + OFF_TRUH;
  int*   last     = (int*)(ws + OFF_LAST);
  float* out      = (float*)d_out;

  hipMemsetAsync(last, 0, NB * sizeof(int), stream);
  k_embed  <<<dim3(NB * NV), dim3(128), 0, stream>>>(diag, mask, table, sumembed, last);
  k_pregemm<<<dim3(512, 7),  dim3(256), 0, stream>>>(sumembed, Wih, bih, bhh, pre);
  k_lstm   <<<dim3(NE),      dim3(256), 0, stream>>>(pre, Whh, last, truh);
  k_fc     <<<dim3(NB),      dim3(128), 0, stream>>>(truh, fcw, fcb, out);
}